// Round 4
// baseline (74.320 us; speedup 1.0000x reference)
//
#include <hip/hip_runtime.h>

#define N_ROWS 600000
#define D_FEAT 128
#define N_SEG 50000
#define CHUNK 64
#define NCHUNK (N_ROWS / CHUNK)   // 9375 exactly (600000 % 64 == 0)

// Accumulate rows [rbeg, rend) of x (float2 per lane) into acc, 4-way unrolled
// with independent partials for memory-level parallelism.
__device__ __forceinline__ void accum_rows(const float2* __restrict__ x2,
                                           int rbeg, int rend, int lane,
                                           float2& acc) {
    float2 a0 = acc, a1{0.f, 0.f}, a2{0.f, 0.f}, a3{0.f, 0.f};
    int r = rbeg;
    for (; r + 4 <= rend; r += 4) {
        float2 v0 = x2[(long)(r + 0) * 64 + lane];
        float2 v1 = x2[(long)(r + 1) * 64 + lane];
        float2 v2 = x2[(long)(r + 2) * 64 + lane];
        float2 v3 = x2[(long)(r + 3) * 64 + lane];
        a0.x += v0.x; a0.y += v0.y;
        a1.x += v1.x; a1.y += v1.y;
        a2.x += v2.x; a2.y += v2.y;
        a3.x += v3.x; a3.y += v3.y;
    }
    for (; r < rend; ++r) {
        float2 v = x2[(long)r * 64 + lane];
        a0.x += v.x; a0.y += v.y;
    }
    acc.x = (a0.x + a1.x) + (a2.x + a3.x);
    acc.y = (a0.y + a1.y) + (a2.y + a3.y);
}

// One wave per 64-row chunk. A wave owns every run (maximal group of equal
// indices) whose START row lies in its chunk; the last owned run may extend
// past the chunk end (those continuation rows are skipped by later waves,
// since they are not run starts). Empty segments are zero-filled by the wave
// owning the index jump. => each x row read once, each out row written once,
// no atomics, no separate offsets pass, near-perfect row balance.
__global__ __launch_bounds__(256) void SegmentSum_20272245637565_kernel(
    const float* __restrict__ x, const int* __restrict__ idx,
    float* __restrict__ out) {
    const int wid = blockIdx.x * 4 + (threadIdx.x >> 6);
    if (wid >= NCHUNK) return;
    const int lane = threadIdx.x & 63;
    const int base = wid * CHUNK;

    const float2* __restrict__ x2 = reinterpret_cast<const float2*>(x);
    float2* __restrict__ out2 = reinterpret_cast<float2*>(out);

    int my = idx[base + lane];                 // one coalesced 256 B load
    int left = __shfl_up(my, 1, 64);
    if (lane == 0) left = (base > 0) ? idx[base - 1] : -1;
    unsigned long long starts = __ballot(my != left);

    // Trailing empty segments (beyond the last index) owned by the last chunk.
    if (wid == NCHUNK - 1) {
        int lastv = __shfl(my, 63, 64);
        for (int e = lastv + 1; e < N_SEG; ++e)
            out2[(long)e * 64 + lane] = make_float2(0.f, 0.f);
    }
    if (!starts) return;                       // pure continuation chunk

    int p = __ffsll(starts) - 1;               // first run start in chunk
    while (true) {
        const int seg     = __shfl(my, p, 64);
        const int prevSeg = __shfl(left, p, 64);
        // Empty segments between the previous index value and this run.
        for (int e = prevSeg + 1; e < seg; ++e)
            out2[(long)e * 64 + lane] = make_float2(0.f, 0.f);

        unsigned long long rest = (p < 63) ? (starts >> (p + 1)) : 0ull;
        float2 acc = make_float2(0.f, 0.f);
        if (rest) {
            const int nextp = p + 1 + (__ffsll(rest) - 1);
            accum_rows(x2, base + p, base + nextp, lane, acc);
            out2[(long)seg * 64 + lane] = acc;
            p = nextp;
        } else {
            // Last owned run: to chunk end, then extend beyond while it continues.
            accum_rows(x2, base + p, base + CHUNK, lane, acc);
            int nb = base + CHUNK;
            while (nb < N_ROWS) {
                int m2 = idx[nb + lane];       // next chunk's indices
                unsigned long long cont = __ballot(m2 == seg);
                int cnt = (~cont) ? (__ffsll(~cont) - 1) : 64;  // leading run rows
                if (cnt > 0) accum_rows(x2, nb, nb + cnt, lane, acc);
                if (cnt < 64) break;
                nb += CHUNK;
            }
            out2[(long)seg * 64 + lane] = acc;
            break;
        }
    }
}

extern "C" void kernel_launch(void* const* d_in, const int* in_sizes, int n_in,
                              void* d_out, int out_size, void* d_ws, size_t ws_size,
                              hipStream_t stream) {
    const float* x  = (const float*)d_in[0];
    const int* idx  = (const int*)d_in[1];
    float* out      = (float*)d_out;

    const int nblocks = (NCHUNK + 3) / 4;      // 4 waves per 256-thread block
    SegmentSum_20272245637565_kernel<<<nblocks, 256, 0, stream>>>(x, idx, out);
}

// Round 5
// 71.881 us; speedup vs baseline: 1.0339x; 1.0339x over previous
//
#include <hip/hip_runtime.h>

#define N_ROWS 600000
#define D_FEAT 128
#define N_SEG 50000
#define SPW 4                     // segments per wave (N_SEG % SPW == 0)

// Pass 1: offsets[s] = first row r with idx[r] >= s, for s in [0, N_SEG].
__global__ __launch_bounds__(256) void seg_offsets_kernel(
    const int* __restrict__ idx, int* __restrict__ offsets) {
    int r = blockIdx.x * 256 + threadIdx.x;
    if (r >= N_ROWS) return;
    int cur = idx[r];
    int prev = (r == 0) ? -1 : idx[r - 1];
    for (int s = prev + 1; s <= cur; ++s) offsets[s] = r;
    if (r == N_ROWS - 1)
        for (int s = cur + 1; s <= N_SEG; ++s) offsets[s] = N_ROWS;
}

// Pass 2: one wave per SPW consecutive segments (4 waves / 256-thread block).
// Wave's x-read stream is a single contiguous ~48-row region. Boundaries for
// all SPW segments come from ONE coalesced load + shfl broadcast.
// Lane t owns columns [2t, 2t+1] (float2). Unroll x4 -> 4 loads in flight.
__global__ __launch_bounds__(256) void SegmentSum_20272245637565_kernel(
    const float* __restrict__ x, const int* __restrict__ offsets,
    float* __restrict__ out) {
    const int wave = threadIdx.x >> 6;
    const int lane = threadIdx.x & 63;
    const int s0   = (blockIdx.x * 4 + wave) * SPW;

    // offsets[s0 .. s0+SPW] in one vector load (lanes 0..SPW)
    int off_l = 0;
    if (lane <= SPW) off_l = offsets[s0 + lane];

    const float2* __restrict__ x2 = reinterpret_cast<const float2*>(x);
    float2* __restrict__ out2 = reinterpret_cast<float2*>(out);

#pragma unroll
    for (int k = 0; k < SPW; ++k) {
        const int start = __shfl(off_l, k, 64);
        const int end   = __shfl(off_l, k + 1, 64);

        float2 a0{0.f, 0.f}, a1{0.f, 0.f}, a2{0.f, 0.f}, a3{0.f, 0.f};
        int r = start;
        for (; r + 4 <= end; r += 4) {
            float2 v0 = x2[(long)(r + 0) * 64 + lane];
            float2 v1 = x2[(long)(r + 1) * 64 + lane];
            float2 v2 = x2[(long)(r + 2) * 64 + lane];
            float2 v3 = x2[(long)(r + 3) * 64 + lane];
            a0.x += v0.x; a0.y += v0.y;
            a1.x += v1.x; a1.y += v1.y;
            a2.x += v2.x; a2.y += v2.y;
            a3.x += v3.x; a3.y += v3.y;
        }
        for (; r < end; ++r) {
            float2 v = x2[(long)r * 64 + lane];
            a0.x += v.x; a0.y += v.y;
        }
        float2 acc;
        acc.x = (a0.x + a1.x) + (a2.x + a3.x);
        acc.y = (a0.y + a1.y) + (a2.y + a3.y);
        out2[(long)(s0 + k) * 64 + lane] = acc;
    }
}

extern "C" void kernel_launch(void* const* d_in, const int* in_sizes, int n_in,
                              void* d_out, int out_size, void* d_ws, size_t ws_size,
                              hipStream_t stream) {
    const float* x  = (const float*)d_in[0];
    const int* idx  = (const int*)d_in[1];
    float* out      = (float*)d_out;
    int* offsets    = (int*)d_ws;   // (N_SEG + 1) ints = 200 KB

    seg_offsets_kernel<<<(N_ROWS + 255) / 256, 256, 0, stream>>>(idx, offsets);
    SegmentSum_20272245637565_kernel<<<N_SEG / (4 * SPW), 256, 0, stream>>>(x, offsets, out);
}

// Round 7
// 61.365 us; speedup vs baseline: 1.2111x; 1.1714x over previous
//
#include <hip/hip_runtime.h>

#define N_ROWS 600000
#define D_FEAT 128
#define N_SEG 50000

typedef float f32x4 __attribute__((ext_vector_type(4)));

// Pass 1: offsets[s] = first row r with idx[r] >= s, for s in [0, N_SEG].
__global__ __launch_bounds__(256) void seg_offsets_kernel(
    const int* __restrict__ idx, int* __restrict__ offsets) {
    int r = blockIdx.x * 256 + threadIdx.x;
    if (r >= N_ROWS) return;
    int cur = idx[r];
    int prev = (r == 0) ? -1 : idx[r - 1];
    for (int s = prev + 1; s <= cur; ++s) offsets[s] = r;
    if (r == N_ROWS - 1)
        for (int s = cur + 1; s <= N_SEG; ++s) offsets[s] = N_ROWS;
}

// Pass 2: one wave per segment, 4 waves per block (best-known structure, R3).
// f32x4 layout: lane = half*32 + col4; two halves cover rows r and r+1 ->
// 2 rows (1 KB) per load instruction, unroll x2 -> 4 rows in flight.
// x is a single-use 307 MB stream and out is write-once -> nontemporal
// accesses keep them from thrashing L2/L3.
__global__ __launch_bounds__(256) void SegmentSum_20272245637565_kernel(
    const float* __restrict__ x, const int* __restrict__ offsets,
    float* __restrict__ out) {
    const int wave = threadIdx.x >> 6;
    const int lane = threadIdx.x & 63;
    const int seg  = blockIdx.x * 4 + wave;

    const int start = offsets[seg];
    const int end   = offsets[seg + 1];

    const int half = lane >> 5;   // row parity within a pair
    const int col4 = lane & 31;   // f32x4 column 0..31

    const f32x4* __restrict__ x4 = reinterpret_cast<const f32x4*>(x);

    f32x4 a0 = {0.f, 0.f, 0.f, 0.f}, a1 = {0.f, 0.f, 0.f, 0.f};
    int r = start;
    for (; r + 4 <= end; r += 4) {
        f32x4 v0 = __builtin_nontemporal_load(&x4[(long)(r + half) * 32 + col4]);
        f32x4 v1 = __builtin_nontemporal_load(&x4[(long)(r + 2 + half) * 32 + col4]);
        a0 += v0;
        a1 += v1;
    }
    if (r + 2 <= end) {
        f32x4 v = __builtin_nontemporal_load(&x4[(long)(r + half) * 32 + col4]);
        a0 += v;
        r += 2;
    }
    if (r < end && half == 0) {
        f32x4 v = __builtin_nontemporal_load(&x4[(long)r * 32 + col4]);
        a0 += v;
    }

    f32x4 s = a0 + a1;

    s.x += __shfl_xor(s.x, 32, 64);
    s.y += __shfl_xor(s.y, 32, 64);
    s.z += __shfl_xor(s.z, 32, 64);
    s.w += __shfl_xor(s.w, 32, 64);

    if (half == 0)
        __builtin_nontemporal_store(s, &reinterpret_cast<f32x4*>(out)[(long)seg * 32 + col4]);
}

extern "C" void kernel_launch(void* const* d_in, const int* in_sizes, int n_in,
                              void* d_out, int out_size, void* d_ws, size_t ws_size,
                              hipStream_t stream) {
    const float* x  = (const float*)d_in[0];
    const int* idx  = (const int*)d_in[1];
    float* out      = (float*)d_out;
    int* offsets    = (int*)d_ws;   // (N_SEG + 1) ints = 200 KB

    seg_offsets_kernel<<<(N_ROWS + 255) / 256, 256, 0, stream>>>(idx, offsets);
    SegmentSum_20272245637565_kernel<<<N_SEG / 4, 256, 0, stream>>>(x, offsets, out);
}

// Round 8
// 61.226 us; speedup vs baseline: 1.2139x; 1.0023x over previous
//
#include <hip/hip_runtime.h>

#define N_ROWS 600000
#define D_FEAT 128
#define N_SEG 50000

typedef float f32x4 __attribute__((ext_vector_type(4)));
typedef int   i32x4 __attribute__((ext_vector_type(4)));

// Pass 1: offsets[s] = first row r with idx[r] >= s, for s in [0, N_SEG].
// One thread per 4 rows: single coalesced int4 NT load; previous row's index
// via __shfl_up (lane 0 falls back to one scalar load). Boundary writes are
// sparse (50001 total across the grid).
__global__ __launch_bounds__(256) void seg_offsets_kernel(
    const int* __restrict__ idx, int* __restrict__ offsets) {
    int q = blockIdx.x * 256 + threadIdx.x;          // quad index
    if (q >= N_ROWS / 4) return;
    const int base = q * 4;

    i32x4 v = __builtin_nontemporal_load(
        reinterpret_cast<const i32x4*>(idx) + q);

    int prev0 = __shfl_up(v.w, 1, 64);
    if ((threadIdx.x & 63) == 0)
        prev0 = (base > 0) ? idx[base - 1] : -1;

    int pv = prev0;
    #pragma unroll
    for (int j = 0; j < 4; ++j) {
        int cur = (j == 0) ? v.x : (j == 1) ? v.y : (j == 2) ? v.z : v.w;
        for (int s = pv + 1; s <= cur; ++s) offsets[s] = base + j;
        pv = cur;
    }
    if (base + 4 == N_ROWS)
        for (int s = pv + 1; s <= N_SEG; ++s) offsets[s] = N_ROWS;
}

// Pass 2: one wave per segment, 4 waves per block (best-known structure).
// f32x4 layout: lane = half*32 + col4; two halves cover rows r and r+1 ->
// 2 rows (1 KB) per load instruction, unroll x2 -> 4 rows in flight.
// Nontemporal on the single-use x stream and write-once out.
__global__ __launch_bounds__(256) void SegmentSum_20272245637565_kernel(
    const float* __restrict__ x, const int* __restrict__ offsets,
    float* __restrict__ out) {
    const int wave = threadIdx.x >> 6;
    const int lane = threadIdx.x & 63;
    const int seg  = blockIdx.x * 4 + wave;

    const int start = offsets[seg];
    const int end   = offsets[seg + 1];

    const int half = lane >> 5;   // row parity within a pair
    const int col4 = lane & 31;   // f32x4 column 0..31

    const f32x4* __restrict__ x4 = reinterpret_cast<const f32x4*>(x);

    f32x4 a0 = {0.f, 0.f, 0.f, 0.f}, a1 = {0.f, 0.f, 0.f, 0.f};
    int r = start;
    for (; r + 4 <= end; r += 4) {
        f32x4 v0 = __builtin_nontemporal_load(&x4[(long)(r + half) * 32 + col4]);
        f32x4 v1 = __builtin_nontemporal_load(&x4[(long)(r + 2 + half) * 32 + col4]);
        a0 += v0;
        a1 += v1;
    }
    if (r + 2 <= end) {
        f32x4 v = __builtin_nontemporal_load(&x4[(long)(r + half) * 32 + col4]);
        a0 += v;
        r += 2;
    }
    if (r < end && half == 0) {
        f32x4 v = __builtin_nontemporal_load(&x4[(long)r * 32 + col4]);
        a0 += v;
    }

    f32x4 s = a0 + a1;

    s.x += __shfl_xor(s.x, 32, 64);
    s.y += __shfl_xor(s.y, 32, 64);
    s.z += __shfl_xor(s.z, 32, 64);
    s.w += __shfl_xor(s.w, 32, 64);

    if (half == 0)
        __builtin_nontemporal_store(s, &reinterpret_cast<f32x4*>(out)[(long)seg * 32 + col4]);
}

extern "C" void kernel_launch(void* const* d_in, const int* in_sizes, int n_in,
                              void* d_out, int out_size, void* d_ws, size_t ws_size,
                              hipStream_t stream) {
    const float* x  = (const float*)d_in[0];
    const int* idx  = (const int*)d_in[1];
    float* out      = (float*)d_out;
    int* offsets    = (int*)d_ws;   // (N_SEG + 1) ints = 200 KB

    seg_offsets_kernel<<<(N_ROWS / 4 + 255) / 256, 256, 0, stream>>>(idx, offsets);
    SegmentSum_20272245637565_kernel<<<N_SEG / 4, 256, 0, stream>>>(x, offsets, out);
}